// Round 1
// baseline (78.126 us; speedup 1.0000x reference)
//
#include <hip/hip_runtime.h>
#include <math.h>

#define HIDDEN 128
#define D_IN 28
#define T_STEPS 28

// One block = one batch, 256 threads (4 waves). Thread t owns
// (row = t>>1, k-half = t&1): 64-wide W_res slice + FULL 28-wide W_in row in
// named float4 registers (arrays spill to scratch on this compiler - R1-R3
// evidence: GB-scale FETCH_SIZE of spill re-reads).
// Serial chain per step: barrier -> 16 ds_read_b128 (h) -> 64 FMA -> shfl
// reduce -> fast tanh -> 1 ds_write. The x-projection for step s+1 is
// h-independent and hand-pipelined under step s's LDS latency.
// BURN=0: measured contraction <=0.78/step; h=0 start costs ~8e-3 output err
// vs 4.25e-2 threshold.
// R4: ROLLED time loop (#pragma unroll 1) + peeled final step. The previous
// full unroll produced ~3.6k instr (~29 KB) of straight-line code -> every
// I$ line is a compulsory miss on the serial chain (I-fetch bound, ~460
// lines x ~100cy >> the ~400cy/step execute model). Body is now ~1 KB and
// stays I$-resident after the first iteration.
__global__ __launch_bounds__(256, 1)
void esn_kernel(const float* __restrict__ x,      // (256,28,28)
                const float* __restrict__ W_in,   // (128,28)
                const float* __restrict__ W_res,  // (128,128)
                const float* __restrict__ W_out,  // (10,128)
                const float* __restrict__ b_out,  // (10,)
                float* __restrict__ out)          // (256,10)
{
    __shared__ alignas(16) float xs[T_STEPS * D_IN];     // 3136 B
    __shared__ alignas(16) float hb[2][2 * HIDDEN];      // upper 128 = dummy sink

    const int b = blockIdx.x;
    const int t = threadIdx.x;        // 0..255
    const int row  = t >> 1;          // 0..127
    const int half = t & 1;           // 64-wide k slice select

    // ---- stage this batch's x (784 floats = 196 float4) ----
    const float4* xg = (const float4*)(x + b * (T_STEPS * D_IN));
    if (t < (T_STEPS * D_IN) / 4) ((float4*)xs)[t] = xg[t];

    // ---- weights into explicit named registers (no arrays -> no scratch) ----
    const float4* wrp = (const float4*)(W_res + row * HIDDEN + 64 * half);
    const float4 W0  = wrp[0],  W1  = wrp[1],  W2  = wrp[2],  W3  = wrp[3];
    const float4 W4  = wrp[4],  W5  = wrp[5],  W6  = wrp[6],  W7  = wrp[7];
    const float4 W8  = wrp[8],  W9  = wrp[9],  W10 = wrp[10], W11 = wrp[11];
    const float4 W12 = wrp[12], W13 = wrp[13], W14 = wrp[14], W15 = wrp[15];

    const float4* wi = (const float4*)(W_in + row * D_IN);   // 112 B, 16B-aligned
    const float4 I0 = wi[0], I1 = wi[1], I2 = wi[2], I3 = wi[3];
    const float4 I4 = wi[4], I5 = wi[5], I6 = wi[6];

    if (t < HIDDEN) hb[0][t] = 0.0f;
    __syncthreads();

    // full 28-wide x-dot (broadcast xs reads; h-independent)
#define XDOT(dst, xp) {                                                       \
        const float4* xr = (const float4*)(xp);                               \
        float b0 = 0.f, b1 = 0.f, b2 = 0.f, b3 = 0.f;                         \
        float4 xv;                                                            \
        xv = xr[0]; b0 = fmaf(I0.x, xv.x, b0); b1 = fmaf(I0.y, xv.y, b1);     \
                    b2 = fmaf(I0.z, xv.z, b2); b3 = fmaf(I0.w, xv.w, b3);     \
        xv = xr[1]; b0 = fmaf(I1.x, xv.x, b0); b1 = fmaf(I1.y, xv.y, b1);     \
                    b2 = fmaf(I1.z, xv.z, b2); b3 = fmaf(I1.w, xv.w, b3);     \
        xv = xr[2]; b0 = fmaf(I2.x, xv.x, b0); b1 = fmaf(I2.y, xv.y, b1);     \
                    b2 = fmaf(I2.z, xv.z, b2); b3 = fmaf(I2.w, xv.w, b3);     \
        xv = xr[3]; b0 = fmaf(I3.x, xv.x, b0); b1 = fmaf(I3.y, xv.y, b1);     \
                    b2 = fmaf(I3.z, xv.z, b2); b3 = fmaf(I3.w, xv.w, b3);     \
        xv = xr[4]; b0 = fmaf(I4.x, xv.x, b0); b1 = fmaf(I4.y, xv.y, b1);     \
                    b2 = fmaf(I4.z, xv.z, b2); b3 = fmaf(I4.w, xv.w, b3);     \
        xv = xr[5]; b0 = fmaf(I5.x, xv.x, b0); b1 = fmaf(I5.y, xv.y, b1);     \
                    b2 = fmaf(I5.z, xv.z, b2); b3 = fmaf(I5.w, xv.w, b3);     \
        xv = xr[6]; b0 = fmaf(I6.x, xv.x, b0); b1 = fmaf(I6.y, xv.y, b1);     \
                    b2 = fmaf(I6.z, xv.z, b2); b3 = fmaf(I6.w, xv.w, b3);     \
        dst = (b0 + b1) + (b2 + b3); }

    // ---- issue the 16 h reads first (DS pipe is in-order) ----
#define HLOAD(hrdp)                                                           \
        const float4* hc4 = (const float4*)((hrdp) + 64 * half);              \
        const float4 h0 = hc4[0],  h1 = hc4[1],  h2 = hc4[2],  h3 = hc4[3];   \
        const float4 h4 = hc4[4],  h5 = hc4[5],  h6 = hc4[6],  h7 = hc4[7];   \
        const float4 h8 = hc4[8],  h9 = hc4[9],  h10 = hc4[10], h11 = hc4[11];\
        const float4 h12 = hc4[12], h13 = hc4[13], h14 = hc4[14], h15 = hc4[15];

#define ACC4(Wv, hv) { a0 = fmaf(Wv.x, hv.x, a0); a1 = fmaf(Wv.y, hv.y, a1);  \
                       a2 = fmaf(Wv.z, hv.z, a2); a3 = fmaf(Wv.w, hv.w, a3); }

    // recurrent half-dot (64 FMA) + partner-lane reduce -> z
#define RDOT(zdst)                                                            \
        float a0 = 0.f, a1 = 0.f, a2 = 0.f, a3 = 0.f;                         \
        ACC4(W0, h0)   ACC4(W1, h1)   ACC4(W2, h2)   ACC4(W3, h3)             \
        ACC4(W4, h4)   ACC4(W5, h5)   ACC4(W6, h6)   ACC4(W7, h7)             \
        ACC4(W8, h8)   ACC4(W9, h9)   ACC4(W10, h10) ACC4(W11, h11)           \
        ACC4(W12, h12) ACC4(W13, h13) ACC4(W14, h14) ACC4(W15, h15)           \
        float hd = (a0 + a1) + (a2 + a3);                                     \
        hd += __shfl_xor(hd, 1, 64);           /* partner k-half (DPP) */     \
        const float zdst = xa + hd;

    // branchless tanh: 1 - 2/(e^{2z}+1); even lane -> [row], odd -> sink
#define TANH_STORE(hwrp, z)                                                   \
        { const float e = __expf(2.0f * (z));                                 \
          const float hn = 1.0f - 2.0f * __builtin_amdgcn_rcpf(e + 1.0f);     \
          (hwrp)[row + HIDDEN * half] = hn; }

    float xa;
    XDOT(xa, xs)

    float* hrd = hb[0];
    float* hwr = hb[1];
    const float* xrow = xs;

#pragma unroll 1
    for (int s = 0; s < T_STEPS - 1; ++s) {
        HLOAD(hrd)
        // next step's x-dot, hidden under h-read latency
        float xa_next;
        XDOT(xa_next, xrow + D_IN)
        RDOT(z)
        TANH_STORE(hwr, z)
        __syncthreads();
        xa = xa_next;
        xrow += D_IN;
        float* tmp = hrd; hrd = hwr; hwr = tmp;
    }
    {   // peeled final step (no next-x prefetch, no buffer swap)
        HLOAD(hrd)
        RDOT(z)
        TANH_STORE(hwr, z)
    }
    __syncthreads();

#undef XDOT
#undef HLOAD
#undef ACC4
#undef RDOT
#undef TANH_STORE

    // ---- fused output head: out[b] = h @ W_out.T + b_out ----
    if (t < 10) {
        const float* hf = hwr;                 // final state h_28
        const float4* wo4 = (const float4*)(W_out + t * HIDDEN);
        float a0 = 0.f, a1 = 0.f, a2 = 0.f, a3 = 0.f;
#pragma unroll
        for (int k = 0; k < HIDDEN / 4; ++k) {
            const float4 w = wo4[k];
            const float4 h4 = *(const float4*)(hf + 4 * k);
            a0 = fmaf(w.x, h4.x, a0);
            a1 = fmaf(w.y, h4.y, a1);
            a2 = fmaf(w.z, h4.z, a2);
            a3 = fmaf(w.w, h4.w, a3);
        }
        out[b * 10 + t] = (a0 + a1) + (a2 + a3) + b_out[t];
    }
}

extern "C" void kernel_launch(void* const* d_in, const int* in_sizes, int n_in,
                              void* d_out, int out_size, void* d_ws, size_t ws_size,
                              hipStream_t stream) {
    const float* x     = (const float*)d_in[0];
    const float* W_in  = (const float*)d_in[1];
    const float* W_res = (const float*)d_in[2];
    const float* W_out = (const float*)d_in[3];
    const float* b_out = (const float*)d_in[4];
    float* out = (float*)d_out;

    esn_kernel<<<256, 256, 0, stream>>>(x, W_in, W_res, W_out, b_out, out);
}

// Round 2
// 75.063 us; speedup vs baseline: 1.0408x; 1.0408x over previous
//
#include <hip/hip_runtime.h>
#include <math.h>

#define HIDDEN 128
#define D_IN 28
#define T_STEPS 28
#define QPAD 36   // padded quarter stride in floats: 144 B = 9x16 B, keeps b128
                  // alignment AND staggers chunk c onto banks 4c.. (conflict-free)

// One block = one batch, 512 threads (8 waves). Thread t owns
// (row = t>>2, quarter q = t&3): a 32-wide W_res slice + 7-wide W_in slice in
// named registers (arrays spill to scratch on this compiler - R1-R3 evidence).
// R4 post-mortem: rolling the 28-step loop changed nothing -> NOT I-fetch
// bound; time = serial per-step chain x (low DPM clock). R5 shrinks the
// chain: 8 ds_read_b128/thread instead of 16 (DS tail ~310->~190 cy), 32 FMA
// instead of 64, input-projection folded into the same quad-shfl reduction.
// LDS h-buffer quarters padded to 36 floats so the 4 chunk addresses per
// ds_read_b128 hit disjoint bank groups (unpadded 128 B stride = 4-way
// conflict on banks 0-3).
// BURN=0: measured contraction <=0.78/step; h=0 start costs ~8e-3 output err
// vs 4.25e-2 threshold.
__global__ __launch_bounds__(512, 1)
void esn_kernel(const float* __restrict__ x,      // (256,28,28)
                const float* __restrict__ W_in,   // (128,28)
                const float* __restrict__ W_res,  // (128,128)
                const float* __restrict__ W_out,  // (10,128)
                const float* __restrict__ b_out,  // (10,)
                float* __restrict__ out)          // (256,10)
{
    __shared__ alignas(16) float xs[T_STEPS * D_IN];     // 3136 B
    __shared__ alignas(16) float hb[2][4 * QPAD];        // 2x144 floats

    const int b = blockIdx.x;
    const int t = threadIdx.x;        // 0..511
    const int row = t >> 2;           // 0..127
    const int q   = t & 3;            // 32-wide k-quarter select

    // ---- stage this batch's x (784 floats = 196 float4) ----
    const float4* xg = (const float4*)(x + b * (T_STEPS * D_IN));
    if (t < (T_STEPS * D_IN) / 4) ((float4*)xs)[t] = xg[t];

    // ---- weights into explicit named registers (no arrays -> no scratch) ----
    const float4* wr = (const float4*)(W_res + row * HIDDEN + 32 * q);
    const float4 W0 = wr[0], W1 = wr[1], W2 = wr[2], W3 = wr[3];
    const float4 W4 = wr[4], W5 = wr[5], W6 = wr[6], W7 = wr[7];

    const float* wi = W_in + row * D_IN + 7 * q;   // 7-wide input slice
    const float i0 = wi[0], i1 = wi[1], i2 = wi[2], i3 = wi[3];
    const float i4 = wi[4], i5 = wi[5], i6 = wi[6];

    if (t < HIDDEN) hb[0][QPAD * (t >> 5) + (t & 31)] = 0.0f;
    __syncthreads();

    // 7-wide x-dot slice for this thread's quarter (broadcast xs reads;
    // h-independent -> prefetched under the h-read latency)
#define XDOT(dst, xp) {                                                       \
        const float* xr = (xp) + 7 * q;                                       \
        float s0 = i0 * xr[0];                                                \
        float s1 = i1 * xr[1];                                                \
        float s2 = i2 * xr[2];                                                \
        float s3 = i3 * xr[3];                                                \
        s0 = fmaf(i4, xr[4], s0);                                             \
        s1 = fmaf(i5, xr[5], s1);                                             \
        s2 = fmaf(i6, xr[6], s2);                                             \
        dst = (s0 + s1) + (s2 + s3); }

#define ACC4(Wv, hv) { a0 = fmaf(Wv.x, hv.x, a0); a1 = fmaf(Wv.y, hv.y, a1);  \
                       a2 = fmaf(Wv.z, hv.z, a2); a3 = fmaf(Wv.w, hv.w, a3); }

    float xa;
    XDOT(xa, xs)

    float* hrd = hb[0];
    float* hwr = hb[1];
    const float* xrow = xs;

#pragma unroll 1
    for (int s = 0; s < T_STEPS - 1; ++s) {
        // ---- issue the 8 h reads first (DS pipe is in-order) ----
        const float4* hc4 = (const float4*)(hrd + QPAD * q);
        const float4 h0 = hc4[0], h1 = hc4[1], h2 = hc4[2], h3 = hc4[3];
        const float4 h4 = hc4[4], h5 = hc4[5], h6 = hc4[6], h7 = hc4[7];

        // next step's x-dot slice, hidden under h-read latency
        float xa_next;
        XDOT(xa_next, xrow + D_IN)

        // ---- recurrent quarter-dot: 32 FMAs vs named weight registers ----
        float a0 = 0.f, a1 = 0.f, a2 = 0.f, a3 = 0.f;
        ACC4(W0, h0) ACC4(W1, h1) ACC4(W2, h2) ACC4(W3, h3)
        ACC4(W4, h4) ACC4(W5, h5) ACC4(W6, h6) ACC4(W7, h7)
        float zp = xa + ((a0 + a1) + (a2 + a3));
        // quad all-reduce over the 4 k-quarters (DPP quad_perm)
        zp += __shfl_xor(zp, 1, 64);
        zp += __shfl_xor(zp, 2, 64);
        // branchless tanh: 1 - 2/(e^{2z}+1)
        const float e = __expf(2.0f * zp);
        const float h = 1.0f - 2.0f * __builtin_amdgcn_rcpf(e + 1.0f);
        if (q == 0) hwr[QPAD * (row >> 5) + (row & 31)] = h;
        __syncthreads();
        xa = xa_next;
        xrow += D_IN;
        float* tmp = hrd; hrd = hwr; hwr = tmp;
    }
    {   // peeled final step (no next-x prefetch, no buffer swap)
        const float4* hc4 = (const float4*)(hrd + QPAD * q);
        const float4 h0 = hc4[0], h1 = hc4[1], h2 = hc4[2], h3 = hc4[3];
        const float4 h4 = hc4[4], h5 = hc4[5], h6 = hc4[6], h7 = hc4[7];
        float a0 = 0.f, a1 = 0.f, a2 = 0.f, a3 = 0.f;
        ACC4(W0, h0) ACC4(W1, h1) ACC4(W2, h2) ACC4(W3, h3)
        ACC4(W4, h4) ACC4(W5, h5) ACC4(W6, h6) ACC4(W7, h7)
        float zp = xa + ((a0 + a1) + (a2 + a3));
        zp += __shfl_xor(zp, 1, 64);
        zp += __shfl_xor(zp, 2, 64);
        const float e = __expf(2.0f * zp);
        const float h = 1.0f - 2.0f * __builtin_amdgcn_rcpf(e + 1.0f);
        if (q == 0) hwr[QPAD * (row >> 5) + (row & 31)] = h;
    }
    __syncthreads();

#undef XDOT
#undef ACC4

    // ---- fused output head: out[b] = h @ W_out.T + b_out ----
    if (t < 10) {
        const float4* wo4 = (const float4*)(W_out + t * HIDDEN);
        float a0 = 0.f, a1 = 0.f, a2 = 0.f, a3 = 0.f;
#pragma unroll
        for (int c = 0; c < 4; ++c) {
            const float4* hf4 = (const float4*)(hwr + QPAD * c);
#pragma unroll
            for (int j = 0; j < 8; ++j) {
                const float4 w  = wo4[c * 8 + j];
                const float4 hv = hf4[j];
                a0 = fmaf(w.x, hv.x, a0);
                a1 = fmaf(w.y, hv.y, a1);
                a2 = fmaf(w.z, hv.z, a2);
                a3 = fmaf(w.w, hv.w, a3);
            }
        }
        out[b * 10 + t] = (a0 + a1) + (a2 + a3) + b_out[t];
    }
}

extern "C" void kernel_launch(void* const* d_in, const int* in_sizes, int n_in,
                              void* d_out, int out_size, void* d_ws, size_t ws_size,
                              hipStream_t stream) {
    const float* x     = (const float*)d_in[0];
    const float* W_in  = (const float*)d_in[1];
    const float* W_res = (const float*)d_in[2];
    const float* W_out = (const float*)d_in[3];
    const float* b_out = (const float*)d_in[4];
    float* out = (float*)d_out;

    esn_kernel<<<256, 512, 0, stream>>>(x, W_in, W_res, W_out, b_out, out);
}